// Round 12
// baseline (233.976 us; speedup 1.0000x reference)
//
#include <hip/hip_runtime.h>

#define N_NODES 100000
#define N_EDGES 1600000
#define D 128
#define N_STRIPS (N_NODES / 32)     // 3125

#define BSH   9                     // bucket = col >> 9 (512 nodes/bucket)
#define NBKT  196                   // ceil(100000 / 512)
#define P_BLK 1000                  // scatter blocks; EPB = 1600 exactly
#define EPB   (N_EDGES / P_BLK)
#define ARENA 9216                  // per-bucket arena slots (mean 8163 + ~12 sigma)

typedef __bf16 bf16x4 __attribute__((ext_vector_type(4)));
typedef __bf16 bf16x8 __attribute__((ext_vector_type(8)));
typedef float  f32x4  __attribute__((ext_vector_type(4)));

// ---- K1: self-reserving coalesced scatter, 512-thread blocks (8-wave barrier
// groups instead of 16). Each block LDS-sorts its 1600-edge slice by bucket,
// reserves one arena window per bucket via a single global atomicAdd, then
// writes bucket-runs coalesced. Block P_BLK casts W. ----
__global__ __launch_bounds__(512) void k_scatter(const int* __restrict__ row,
                                                 const int* __restrict__ col,
                                                 const float4* __restrict__ w4,
                                                 int* __restrict__ gcnt,
                                                 unsigned* __restrict__ grec,
                                                 bf16x4* __restrict__ wb4) {
    int b = blockIdx.x, t = threadIdx.x;
    if (b == P_BLK) {                      // cast W -> bf16 (4096 float4)
        for (int i = t; i < (D * D) / 4; i += 512) {
            float4 u = w4[i];
            bf16x4 p;
            p[0] = (__bf16)u.x; p[1] = (__bf16)u.y;
            p[2] = (__bf16)u.z; p[3] = (__bf16)u.w;
            wb4[i] = p;
        }
        return;
    }
    __shared__ int      rec[EPB];          // packed (row<<9 | col&511)
    __shared__ unsigned short kb[EPB];     // bucket id per edge
    __shared__ int      srt[EPB];          // bucket-sorted records
    __shared__ int      dofp[EPB];         // per-record global offset delta
    __shared__ int      lh[256];           // local hist
    __shared__ int      sc[256];           // exclusive scan
    __shared__ int      cur[256];          // placement cursors
    __shared__ int      dofk[256];         // per-bucket dst delta
    if (t < 256) lh[t] = 0;
    __syncthreads();
    int e0 = b * EPB;
    for (int i = t; i < EPB; i += 512) {
        int r = row[e0 + i], c = col[e0 + i];
        int k = c >> BSH;
        rec[i] = (r << BSH) | (c & ((1 << BSH) - 1));
        kb[i]  = (unsigned short)k;
        atomicAdd(&lh[k], 1);
    }
    __syncthreads();
    int v = 0;
    if (t < 256) { v = lh[t]; sc[t] = v; }
    __syncthreads();
    for (int off = 1; off < 256; off <<= 1) {
        int u = 0;
        if (t < 256 && t >= off) u = sc[t - off];
        __syncthreads();
        if (t < 256) sc[t] += u;
        __syncthreads();
    }
    if (t < 256) {
        int excl = sc[t] - v;              // local exclusive base
        sc[t]  = excl;
        cur[t] = 0;
        int base = (t < NBKT && v > 0) ? atomicAdd(&gcnt[t], v) : 0;
        dofk[t] = t * ARENA + base - excl; // global dst = local pos + dofk
    }
    __syncthreads();
    for (int i = t; i < EPB; i += 512) {
        int k = kb[i];
        int p = sc[k] + atomicAdd(&cur[k], 1);
        srt[p]  = rec[i];
        dofp[p] = dofk[k];
    }
    __syncthreads();
    for (int i = t; i < EPB; i += 512) {
        unsigned dst = (unsigned)(i + dofp[i]);
        if (dst < (unsigned)(NBKT * ARENA))         // defensive (12-sigma)
            grec[dst] = (unsigned)srt[i];
    }
}

// ---- K2: per-bucket fine counting sort, 512-thread blocks, bucket cached in
// LDS; emits deg/dis/start and rewrites arena in place as srcs byte offsets ----
__global__ __launch_bounds__(512) void k_fine(unsigned* __restrict__ grec,
                                              const int* __restrict__ gcnt,
                                              int* __restrict__ deg,
                                              float* __restrict__ dis,
                                              int* __restrict__ start) {
    __shared__ unsigned cache[ARENA];
    __shared__ int fh[512];
    __shared__ int fsc[512];
    int b = blockIdx.x;
    int tid = threadIdx.x;
    int cnt = gcnt[b]; if (cnt > ARENA) cnt = ARENA;
    int gs = b * ARENA;
    fh[tid] = 0;
    __syncthreads();
    for (int i = tid; i < cnt; i += 512) {
        unsigned r = grec[gs + i];
        cache[i] = r;
        atomicAdd(&fh[r & 511], 1);
    }
    __syncthreads();
    int v = fh[tid];
    fsc[tid] = v;
    __syncthreads();
    for (int off = 1; off < 512; off <<= 1) {
        int u = (tid >= off) ? fsc[tid - off] : 0;
        __syncthreads();
        fsc[tid] += u;
        __syncthreads();
    }
    {
        int excl = fsc[tid] - v;              // exclusive scan value
        int node = (b << BSH) + tid;
        if (node < N_NODES) {
            deg[node]   = v;
            dis[node]   = rsqrtf((float)v + 1.0f);
            start[node] = gs + excl;
        }
        fh[tid] = excl;                       // -> cursors
    }
    __syncthreads();
    for (int i = tid; i < cnt; i += 512) {
        unsigned r = cache[i];
        int pos = atomicAdd(&fh[r & 511], 1);
        grec[gs + pos] = (r >> BSH) << 8;     // row * 256 = byte offset into hb
    }
}

// ---- K3: transform-first: hb[row] = bf16( (x @ W^T)[row] * dis[row] ) ----
__global__ __launch_bounds__(256) void k_hx(const float* __restrict__ x,
                                            const __bf16* __restrict__ wb,
                                            const float* __restrict__ dis,
                                            __bf16* __restrict__ hb) {
    int wave = threadIdx.x >> 6;
    int lane = threadIdx.x & 63;
    int strip = blockIdx.x * 4 + wave;
    if (strip >= N_STRIPS) return;
    int m0 = strip * 32;
    int l15 = lane & 15;
    int kq  = lane >> 4;

    bf16x8 a[2][4];
    #pragma unroll
    for (int mt = 0; mt < 2; ++mt) {
        const float* ap = x + (size_t)(m0 + mt * 16 + l15) * D + kq * 8;
        #pragma unroll
        for (int ks = 0; ks < 4; ++ks) {
            float4 lo = *(const float4*)(ap + ks * 32);
            float4 hi = *(const float4*)(ap + ks * 32 + 4);
            bf16x8 t;
            t[0] = (__bf16)lo.x; t[1] = (__bf16)lo.y;
            t[2] = (__bf16)lo.z; t[3] = (__bf16)lo.w;
            t[4] = (__bf16)hi.x; t[5] = (__bf16)hi.y;
            t[6] = (__bf16)hi.z; t[7] = (__bf16)hi.w;
            a[mt][ks] = t;
        }
    }

    f32x4 acc[2][8] = {};
    #pragma unroll
    for (int ks = 0; ks < 4; ++ks) {
        #pragma unroll
        for (int nt = 0; nt < 8; ++nt) {
            bf16x8 b = *(const bf16x8*)(wb + (size_t)(nt * 16 + l15) * D + ks * 32 + kq * 8);
            acc[0][nt] = __builtin_amdgcn_mfma_f32_16x16x32_bf16(a[0][ks], b, acc[0][nt], 0, 0, 0);
            acc[1][nt] = __builtin_amdgcn_mfma_f32_16x16x32_bf16(a[1][ks], b, acc[1][nt], 0, 0, 0);
        }
    }

    float dsv[2][4];
    #pragma unroll
    for (int mt = 0; mt < 2; ++mt)
        #pragma unroll
        for (int r = 0; r < 4; ++r)
            dsv[mt][r] = dis[m0 + mt * 16 + kq * 4 + r];

    #pragma unroll
    for (int nt = 0; nt < 8; ++nt) {
        int colj = nt * 16 + l15;
        #pragma unroll
        for (int mt = 0; mt < 2; ++mt) {
            #pragma unroll
            for (int r = 0; r < 4; ++r) {
                int rowi = m0 + mt * 16 + kq * 4 + r;
                hb[(size_t)rowi * D + colj] = (__bf16)(acc[mt][nt][r] * dsv[mt][r]);
            }
        }
    }
}

// ---- K4: gather-aggregate: one wave per destination; FOUR source rows per
// VMEM instruction (4 quarter-groups x 16 lanes x dwordx4) ----
__global__ __launch_bounds__(256) void k_aggregate(const int* __restrict__ srcs,
                                                   const int* __restrict__ start,
                                                   const int* __restrict__ deg,
                                                   const __bf16* __restrict__ hb,
                                                   const float* __restrict__ dis,
                                                   const float* __restrict__ bias,
                                                   float* __restrict__ out) {
    int node = (blockIdx.x * 256 + threadIdx.x) >> 6;
    int lane = threadIdx.x & 63;
    if (node >= N_NODES) return;
    int li = lane & 15;            // 16B slot within row (cols 8*li .. 8*li+7)
    int q  = lane >> 4;            // quarter: which of 4 edges per instruction
    int s = start[node];
    int n = deg[node];
    float dc = dis[node];
    const unsigned char* hbase = (const unsigned char*)hb;
    size_t boff = (size_t)li * 16;

    float a0 = 0.f, a1 = 0.f, a2 = 0.f, a3 = 0.f;
    float a4 = 0.f, a5 = 0.f, a6 = 0.f, a7 = 0.f;

#define ACC8(v)                                          \
    do {                                                 \
        a0 += __uint_as_float((v).x << 16);              \
        a1 += __uint_as_float((v).x & 0xFFFF0000u);      \
        a2 += __uint_as_float((v).y << 16);              \
        a3 += __uint_as_float((v).y & 0xFFFF0000u);      \
        a4 += __uint_as_float((v).z << 16);              \
        a5 += __uint_as_float((v).z & 0xFFFF0000u);      \
        a6 += __uint_as_float((v).w << 16);              \
        a7 += __uint_as_float((v).w & 0xFFFF0000u);      \
    } while (0)

    for (int base = 0; base < n; base += 64) {
        int m = n - base; if (m > 64) m = 64;
        int src_l = (lane < m) ? srcs[s + base + lane] : 0;   // byte offsets
        int i = 0;
        for (; i + 16 <= m; i += 16) {          // 16 edges per batch (4 per instr)
            int sv[4]; uint4 av[4];
            #pragma unroll
            for (int j = 0; j < 4; ++j)
                sv[j] = __shfl(src_l, i + 4 * j + q);
            #pragma unroll
            for (int j = 0; j < 4; ++j)
                av[j] = *(const uint4*)(hbase + ((size_t)sv[j] + boff));
            #pragma unroll
            for (int j = 0; j < 4; ++j)
                ACC8(av[j]);
        }
        for (; i + 4 <= m; i += 4) {            // 4 edges per step
            int sj = __shfl(src_l, i + q);
            uint4 a = *(const uint4*)(hbase + ((size_t)sj + boff));
            ACC8(a);
        }
        if (i < m) {                            // tail: r in {1,2,3} edges
            int sj = __shfl(src_l, i + q);
            if (q < m - i) {
                uint4 a = *(const uint4*)(hbase + ((size_t)sj + boff));
                ACC8(a);
            }
        }
    }

    // combine the four quarters
    a0 += __shfl_xor(a0, 16); a0 += __shfl_xor(a0, 32);
    a1 += __shfl_xor(a1, 16); a1 += __shfl_xor(a1, 32);
    a2 += __shfl_xor(a2, 16); a2 += __shfl_xor(a2, 32);
    a3 += __shfl_xor(a3, 16); a3 += __shfl_xor(a3, 32);
    a4 += __shfl_xor(a4, 16); a4 += __shfl_xor(a4, 32);
    a5 += __shfl_xor(a5, 16); a5 += __shfl_xor(a5, 32);
    a6 += __shfl_xor(a6, 16); a6 += __shfl_xor(a6, 32);
    a7 += __shfl_xor(a7, 16); a7 += __shfl_xor(a7, 32);

    if (q == 0) {
        // self-loop term (hb already prescaled by dis[node])
        uint4 a = *(const uint4*)(hbase + ((size_t)node * 256 + boff));
        ACC8(a);

        float4 b0 = *(const float4*)(bias + li * 8);
        float4 b1 = *(const float4*)(bias + li * 8 + 4);
        float4 r0, r1;
        r0.x = fmaxf(a0 * dc + b0.x, 0.f);
        r0.y = fmaxf(a1 * dc + b0.y, 0.f);
        r0.z = fmaxf(a2 * dc + b0.z, 0.f);
        r0.w = fmaxf(a3 * dc + b0.w, 0.f);
        r1.x = fmaxf(a4 * dc + b1.x, 0.f);
        r1.y = fmaxf(a5 * dc + b1.y, 0.f);
        r1.z = fmaxf(a6 * dc + b1.z, 0.f);
        r1.w = fmaxf(a7 * dc + b1.w, 0.f);
        *(float4*)(out + (size_t)node * D + li * 8)     = r0;
        *(float4*)(out + (size_t)node * D + li * 8 + 4) = r1;
    }
#undef ACC8
}

extern "C" void kernel_launch(void* const* d_in, const int* in_sizes, int n_in,
                              void* d_out, int out_size, void* d_ws, size_t ws_size,
                              hipStream_t stream) {
    const float* x    = (const float*)d_in[0];
    const int*   ei   = (const int*)d_in[1];    // [2, E]: row then col
    const float* w    = (const float*)d_in[2];
    const float* bias = (const float*)d_in[3];
    float* out = (float*)d_out;

    char* ws = (char*)d_ws;
    int*      deg    = (int*)ws;              ws += N_NODES * 4;
    float*    dis    = (float*)ws;            ws += N_NODES * 4;
    int*      start  = (int*)ws;              ws += N_NODES * 4;
    int*      gcnt   = (int*)ws;              ws += 256 * 4;
    __bf16*   wb     = (__bf16*)ws;           ws += D * D * 2;
    unsigned* arena  = (unsigned*)ws;         ws += (size_t)NBKT * ARENA * 4;  // grec -> srcs in place
    __bf16*   hb     = (__bf16*)ws;           // N_NODES * D * 2 = 25.6 MB

    const int* row = ei;
    const int* col = ei + N_EDGES;

    hipMemsetAsync(gcnt, 0, 256 * 4, stream);
    k_scatter  <<<P_BLK + 1, 512, 0, stream>>>(row, col, (const float4*)w, gcnt, arena, (bf16x4*)wb);
    k_fine     <<<NBKT, 512, 0, stream>>>(arena, gcnt, deg, dis, start);
    k_hx       <<<(N_STRIPS + 3) / 4, 256, 0, stream>>>(x, wb, dis, hb);
    k_aggregate<<<(N_NODES * 64 + 255) / 256, 256, 0, stream>>>((const int*)arena, start, deg, hb, dis, bias, out);
}

// Round 13
// 222.674 us; speedup vs baseline: 1.0508x; 1.0508x over previous
//
#include <hip/hip_runtime.h>

#define N_NODES 100000
#define N_EDGES 1600000
#define D 128
#define N_STRIPS (N_NODES / 32)     // 3125

#define BSH   9                     // bucket = col >> 9 (512 nodes/bucket)
#define NBKT  196                   // ceil(100000 / 512)
#define P_BLK 512                   // scatter blocks; EPB = 3125 exactly
#define EPB   (N_EDGES / P_BLK)
#define ARENA 9216                  // per-bucket arena slots (mean 8163 + ~12 sigma)

typedef __bf16 bf16x4 __attribute__((ext_vector_type(4)));
typedef __bf16 bf16x8 __attribute__((ext_vector_type(8)));
typedef float  f32x4  __attribute__((ext_vector_type(4)));

__device__ __forceinline__ void acc8(float (&a)[8], uint4 v) {
    a[0] += __uint_as_float(v.x << 16);
    a[1] += __uint_as_float(v.x & 0xFFFF0000u);
    a[2] += __uint_as_float(v.y << 16);
    a[3] += __uint_as_float(v.y & 0xFFFF0000u);
    a[4] += __uint_as_float(v.z << 16);
    a[5] += __uint_as_float(v.z & 0xFFFF0000u);
    a[6] += __uint_as_float(v.w << 16);
    a[7] += __uint_as_float(v.w & 0xFFFF0000u);
}

// generic (rare) per-node gather: 4 edges per VMEM step
__device__ __forceinline__ void gather_node(const int* __restrict__ srcs,
                                            int s, int n,
                                            const unsigned char* hbase,
                                            size_t boff, int lane, int q,
                                            float (&acc)[8]) {
    for (int base = 0; base < n; base += 64) {
        int m = n - base; if (m > 64) m = 64;
        int src_l = (lane < m) ? srcs[s + base + lane] : 0;
        int i = 0;
        for (; i + 4 <= m; i += 4) {
            int sj = __shfl(src_l, i + q);
            uint4 v = *(const uint4*)(hbase + ((size_t)sj + boff));
            acc8(acc, v);
        }
        if (i < m) {
            int sj = __shfl(src_l, i + q);
            if (q < m - i) {
                uint4 v = *(const uint4*)(hbase + ((size_t)sj + boff));
                acc8(acc, v);
            }
        }
    }
}

// ---- K1: self-reserving coalesced scatter (1024-thr). Each block LDS-sorts
// its 3125-edge slice by bucket, reserves one arena window per bucket via a
// single global atomicAdd, then writes bucket-runs coalesced. Block P_BLK
// casts W. ----
__global__ __launch_bounds__(1024) void k_scatter(const int* __restrict__ row,
                                                  const int* __restrict__ col,
                                                  const float4* __restrict__ w4,
                                                  int* __restrict__ gcnt,
                                                  unsigned* __restrict__ grec,
                                                  bf16x4* __restrict__ wb4) {
    int b = blockIdx.x, t = threadIdx.x;
    if (b == P_BLK) {                      // cast W -> bf16 (4096 float4)
        for (int i = t; i < (D * D) / 4; i += 1024) {
            float4 u = w4[i];
            bf16x4 p;
            p[0] = (__bf16)u.x; p[1] = (__bf16)u.y;
            p[2] = (__bf16)u.z; p[3] = (__bf16)u.w;
            wb4[i] = p;
        }
        return;
    }
    __shared__ int      rec[EPB];          // packed (row<<9 | col&511)
    __shared__ unsigned short kb[EPB];     // bucket id per edge
    __shared__ int      srt[EPB];          // bucket-sorted records
    __shared__ int      dofp[EPB];         // per-record global offset delta
    __shared__ int      lh[256];           // local hist
    __shared__ int      sc[256];           // exclusive scan
    __shared__ int      cur[256];          // placement cursors
    __shared__ int      dofk[256];         // per-bucket dst delta
    if (t < 256) lh[t] = 0;
    __syncthreads();
    int e0 = b * EPB;
    for (int i = t; i < EPB; i += 1024) {
        int r = row[e0 + i], c = col[e0 + i];
        int k = c >> BSH;
        rec[i] = (r << BSH) | (c & ((1 << BSH) - 1));
        kb[i]  = (unsigned short)k;
        atomicAdd(&lh[k], 1);
    }
    __syncthreads();
    int v = 0;
    if (t < 256) { v = lh[t]; sc[t] = v; }
    __syncthreads();
    for (int off = 1; off < 256; off <<= 1) {
        int u = 0;
        if (t < 256 && t >= off) u = sc[t - off];
        __syncthreads();
        if (t < 256) sc[t] += u;
        __syncthreads();
    }
    if (t < 256) {
        int excl = sc[t] - v;              // local exclusive base
        sc[t]  = excl;
        cur[t] = 0;
        int base = (t < NBKT && v > 0) ? atomicAdd(&gcnt[t], v) : 0;
        dofk[t] = t * ARENA + base - excl; // global dst = local pos + dofk
    }
    __syncthreads();
    for (int i = t; i < EPB; i += 1024) {
        int k = kb[i];
        int p = sc[k] + atomicAdd(&cur[k], 1);
        srt[p]  = rec[i];
        dofp[p] = dofk[k];
    }
    __syncthreads();
    for (int i = t; i < EPB; i += 1024) {
        unsigned dst = (unsigned)(i + dofp[i]);
        if (dst < (unsigned)(NBKT * ARENA))         // defensive (12-sigma)
            grec[dst] = (unsigned)srt[i];
    }
}

// ---- K2: per-bucket fine counting sort, bucket cached in LDS (one global
// read pass); emits deg/dis/start and rewrites arena in place as srcs
// byte offsets into hb ----
__global__ __launch_bounds__(1024) void k_fine(unsigned* __restrict__ grec,
                                               const int* __restrict__ gcnt,
                                               int* __restrict__ deg,
                                               float* __restrict__ dis,
                                               int* __restrict__ start) {
    __shared__ unsigned cache[ARENA];
    __shared__ int fh[512];
    __shared__ int fsc[512];
    int b = blockIdx.x;
    int tid = threadIdx.x;
    int cnt = gcnt[b]; if (cnt > ARENA) cnt = ARENA;
    int gs = b * ARENA;
    if (tid < 512) fh[tid] = 0;
    __syncthreads();
    for (int i = tid; i < cnt; i += 1024) {
        unsigned r = grec[gs + i];
        cache[i] = r;
        atomicAdd(&fh[r & 511], 1);
    }
    __syncthreads();
    int v = 0;
    if (tid < 512) { v = fh[tid]; fsc[tid] = v; }
    __syncthreads();
    for (int off = 1; off < 512; off <<= 1) {
        int u = 0;
        if (tid < 512 && tid >= off) u = fsc[tid - off];
        __syncthreads();
        if (tid < 512) fsc[tid] += u;
        __syncthreads();
    }
    if (tid < 512) {
        int excl = fsc[tid] - v;              // exclusive scan value
        int node = (b << BSH) + tid;
        if (node < N_NODES) {
            deg[node]   = v;
            dis[node]   = rsqrtf((float)v + 1.0f);
            start[node] = gs + excl;
        }
        fh[tid] = excl;                       // -> cursors
    }
    __syncthreads();
    for (int i = tid; i < cnt; i += 1024) {
        unsigned r = cache[i];
        int pos = atomicAdd(&fh[r & 511], 1);
        grec[gs + pos] = (r >> BSH) << 8;     // row * 256 = byte offset into hb
    }
}

// ---- K3: transform-first: hb[row] = bf16( (x @ W^T)[row] * dis[row] ) ----
__global__ __launch_bounds__(256) void k_hx(const float* __restrict__ x,
                                            const __bf16* __restrict__ wb,
                                            const float* __restrict__ dis,
                                            __bf16* __restrict__ hb) {
    int wave = threadIdx.x >> 6;
    int lane = threadIdx.x & 63;
    int strip = blockIdx.x * 4 + wave;
    if (strip >= N_STRIPS) return;
    int m0 = strip * 32;
    int l15 = lane & 15;
    int kq  = lane >> 4;

    bf16x8 a[2][4];
    #pragma unroll
    for (int mt = 0; mt < 2; ++mt) {
        const float* ap = x + (size_t)(m0 + mt * 16 + l15) * D + kq * 8;
        #pragma unroll
        for (int ks = 0; ks < 4; ++ks) {
            float4 lo = *(const float4*)(ap + ks * 32);
            float4 hi = *(const float4*)(ap + ks * 32 + 4);
            bf16x8 t;
            t[0] = (__bf16)lo.x; t[1] = (__bf16)lo.y;
            t[2] = (__bf16)lo.z; t[3] = (__bf16)lo.w;
            t[4] = (__bf16)hi.x; t[5] = (__bf16)hi.y;
            t[6] = (__bf16)hi.z; t[7] = (__bf16)hi.w;
            a[mt][ks] = t;
        }
    }

    f32x4 acc[2][8] = {};
    #pragma unroll
    for (int ks = 0; ks < 4; ++ks) {
        #pragma unroll
        for (int nt = 0; nt < 8; ++nt) {
            bf16x8 b = *(const bf16x8*)(wb + (size_t)(nt * 16 + l15) * D + ks * 32 + kq * 8);
            acc[0][nt] = __builtin_amdgcn_mfma_f32_16x16x32_bf16(a[0][ks], b, acc[0][nt], 0, 0, 0);
            acc[1][nt] = __builtin_amdgcn_mfma_f32_16x16x32_bf16(a[1][ks], b, acc[1][nt], 0, 0, 0);
        }
    }

    float dsv[2][4];
    #pragma unroll
    for (int mt = 0; mt < 2; ++mt)
        #pragma unroll
        for (int r = 0; r < 4; ++r)
            dsv[mt][r] = dis[m0 + mt * 16 + kq * 4 + r];

    #pragma unroll
    for (int nt = 0; nt < 8; ++nt) {
        int colj = nt * 16 + l15;
        #pragma unroll
        for (int mt = 0; mt < 2; ++mt) {
            #pragma unroll
            for (int r = 0; r < 4; ++r) {
                int rowi = m0 + mt * 16 + kq * 4 + r;
                hb[(size_t)rowi * D + colj] = (__bf16)(acc[mt][nt][r] * dsv[mt][r]);
            }
        }
    }
}

// ---- K4: gather-aggregate, TWO nodes per wave (doubled memory-level
// parallelism: 8 row-loads in flight). 16 lanes x dwordx4 per row, 4 rows
// per VMEM instruction per node. Fast path deg<=64; generic fallback. ----
__global__ __launch_bounds__(256) void k_aggregate(const int* __restrict__ srcs,
                                                   const int* __restrict__ start,
                                                   const int* __restrict__ deg,
                                                   const __bf16* __restrict__ hb,
                                                   const float* __restrict__ dis,
                                                   const float* __restrict__ bias,
                                                   float* __restrict__ out) {
    int wid = (blockIdx.x * 256 + threadIdx.x) >> 6;
    int nodeA = wid * 2;
    if (nodeA >= N_NODES) return;
    int nodeB = nodeA + 1;                 // N_NODES even -> always valid
    int lane = threadIdx.x & 63;
    int li = lane & 15;                    // 16B slot within row
    int q  = lane >> 4;                    // quarter
    const unsigned char* hbase = (const unsigned char*)hb;
    size_t boff = (size_t)li * 16;

    int sA = start[nodeA], nA = deg[nodeA];
    int sB = start[nodeB], nB = deg[nodeB];
    float dA = dis[nodeA], dB = dis[nodeB];

    uint4 selfA = *(const uint4*)(hbase + ((size_t)nodeA * 256 + boff));
    uint4 selfB = *(const uint4*)(hbase + ((size_t)nodeB * 256 + boff));

    float accA[8] = {0.f, 0.f, 0.f, 0.f, 0.f, 0.f, 0.f, 0.f};
    float accB[8] = {0.f, 0.f, 0.f, 0.f, 0.f, 0.f, 0.f, 0.f};

    if (nA <= 64 && nB <= 64) {
        int srcA = (lane < nA) ? srcs[sA + lane] : 0;   // byte offsets
        int srcB = (lane < nB) ? srcs[sB + lane] : 0;
        int nmax = nA > nB ? nA : nB;
        #pragma unroll
        for (int i = 0; i < 64; i += 16) {
            if (i >= nmax) break;
            int svA[4], svB[4];
            #pragma unroll
            for (int j = 0; j < 4; ++j) {
                svA[j] = __shfl(srcA, i + 4 * j + q);
                svB[j] = __shfl(srcB, i + 4 * j + q);
            }
            uint4 avA[4], avB[4];
            if (i < nA) {
                #pragma unroll
                for (int j = 0; j < 4; ++j)
                    avA[j] = *(const uint4*)(hbase + ((size_t)svA[j] + boff));
            }
            if (i < nB) {
                #pragma unroll
                for (int j = 0; j < 4; ++j)
                    avB[j] = *(const uint4*)(hbase + ((size_t)svB[j] + boff));
            }
            if (i < nA) {
                #pragma unroll
                for (int j = 0; j < 4; ++j)
                    if (i + 4 * j + q < nA) acc8(accA, avA[j]);
            }
            if (i < nB) {
                #pragma unroll
                for (int j = 0; j < 4; ++j)
                    if (i + 4 * j + q < nB) acc8(accB, avB[j]);
            }
        }
    } else {
        gather_node(srcs, sA, nA, hbase, boff, lane, q, accA);
        gather_node(srcs, sB, nB, hbase, boff, lane, q, accB);
    }

    // combine the four quarters
    #pragma unroll
    for (int k = 0; k < 8; ++k) {
        accA[k] += __shfl_xor(accA[k], 16);
        accA[k] += __shfl_xor(accA[k], 32);
        accB[k] += __shfl_xor(accB[k], 16);
        accB[k] += __shfl_xor(accB[k], 32);
    }

    if (q == 0) {
        // self-loop terms (hb already prescaled by dis[node])
        acc8(accA, selfA);
        acc8(accB, selfB);

        float4 b0 = *(const float4*)(bias + li * 8);
        float4 b1 = *(const float4*)(bias + li * 8 + 4);
        float4 r0, r1;
        r0.x = fmaxf(accA[0] * dA + b0.x, 0.f);
        r0.y = fmaxf(accA[1] * dA + b0.y, 0.f);
        r0.z = fmaxf(accA[2] * dA + b0.z, 0.f);
        r0.w = fmaxf(accA[3] * dA + b0.w, 0.f);
        r1.x = fmaxf(accA[4] * dA + b1.x, 0.f);
        r1.y = fmaxf(accA[5] * dA + b1.y, 0.f);
        r1.z = fmaxf(accA[6] * dA + b1.z, 0.f);
        r1.w = fmaxf(accA[7] * dA + b1.w, 0.f);
        *(float4*)(out + (size_t)nodeA * D + li * 8)     = r0;
        *(float4*)(out + (size_t)nodeA * D + li * 8 + 4) = r1;

        r0.x = fmaxf(accB[0] * dB + b0.x, 0.f);
        r0.y = fmaxf(accB[1] * dB + b0.y, 0.f);
        r0.z = fmaxf(accB[2] * dB + b0.z, 0.f);
        r0.w = fmaxf(accB[3] * dB + b0.w, 0.f);
        r1.x = fmaxf(accB[4] * dB + b1.x, 0.f);
        r1.y = fmaxf(accB[5] * dB + b1.y, 0.f);
        r1.z = fmaxf(accB[6] * dB + b1.z, 0.f);
        r1.w = fmaxf(accB[7] * dB + b1.w, 0.f);
        *(float4*)(out + (size_t)nodeB * D + li * 8)     = r0;
        *(float4*)(out + (size_t)nodeB * D + li * 8 + 4) = r1;
    }
}

extern "C" void kernel_launch(void* const* d_in, const int* in_sizes, int n_in,
                              void* d_out, int out_size, void* d_ws, size_t ws_size,
                              hipStream_t stream) {
    const float* x    = (const float*)d_in[0];
    const int*   ei   = (const int*)d_in[1];    // [2, E]: row then col
    const float* w    = (const float*)d_in[2];
    const float* bias = (const float*)d_in[3];
    float* out = (float*)d_out;

    char* ws = (char*)d_ws;
    int*      deg    = (int*)ws;              ws += N_NODES * 4;
    float*    dis    = (float*)ws;            ws += N_NODES * 4;
    int*      start  = (int*)ws;              ws += N_NODES * 4;
    int*      gcnt   = (int*)ws;              ws += 256 * 4;
    __bf16*   wb     = (__bf16*)ws;           ws += D * D * 2;
    unsigned* arena  = (unsigned*)ws;         ws += (size_t)NBKT * ARENA * 4;  // grec -> srcs in place
    __bf16*   hb     = (__bf16*)ws;           // N_NODES * D * 2 = 25.6 MB

    const int* row = ei;
    const int* col = ei + N_EDGES;

    hipMemsetAsync(gcnt, 0, 256 * 4, stream);
    k_scatter  <<<P_BLK + 1, 1024, 0, stream>>>(row, col, (const float4*)w, gcnt, arena, (bf16x4*)wb);
    k_fine     <<<NBKT, 1024, 0, stream>>>(arena, gcnt, deg, dis, start);
    k_hx       <<<(N_STRIPS + 3) / 4, 256, 0, stream>>>(x, wb, dis, hb);
    k_aggregate<<<(N_NODES / 2 * 64) / 256, 256, 0, stream>>>((const int*)arena, start, deg, hb, dis, bias, out);
}